// Round 10
// baseline (120.330 us; speedup 1.0000x reference)
//
#include <hip/hip_runtime.h>

#define DEPTH 8
#define BDEPTH 10
#define BATCH 4096
#define NIN 784
#define HALF 512
#define SPLINE_DIM 20
#define NQ 18

typedef __attribute__((ext_vector_type(8))) short bf16x8;
typedef __attribute__((ext_vector_type(4))) float f32x4;

__device__ float d_T[23] = {
  -8.f, -8.f, -8.f, -4.f, -2.f, -1.f, -0.5f, -0.25f, -0.125f, -0.0625f,
  -0.03125f, 0.f, 0.03125f, 0.0625f, 0.125f, 0.25f, 0.5f, 1.f, 2.f, 4.f,
  8.f, 8.f, 8.f };

// logical index n of slot at step d: n bit b = slot bit (b-d) mod 10  (validated R1-R9)
__device__ __forceinline__ int slot_to_n(int slot, int d) {
  int n = 0;
#pragma unroll
  for (int bb = 0; bb < 10; ++bb) { int src = bb - d; if (src < 0) src += 10; n |= ((slot >> src) & 1) << bb; }
  return n;
}

__device__ __forceinline__ unsigned short f2bf(float x) {  // RNE f32->bf16
  unsigned u = __float_as_uint(x);
  unsigned r = (u + 0x7fffu + ((u >> 16) & 1u)) >> 16;
  return (unsigned short)r;
}

// ---------------------------------------------------------------------------
// prepA: c0 (step-0 pair rotations), M8 (composed steps 1-3 as 8x8 rows),
//        qt (per-interval quadratic spline, unchanged from validated R3+).
// ---------------------------------------------------------------------------
__global__ void prepA(const float* __restrict__ bp, const float* __restrict__ sc,
                      float2* __restrict__ c0, float* __restrict__ M8,
                      float4* __restrict__ qt) {
  int gid = blockIdx.x * 256 + threadIdx.x;
  if (gid < 4096) {                       // c0[i*512 + wv*64 + p]
    int i = gid >> 9, rem = gid & 511;    // slot = rem (g3=0); d=0 -> n = slot
    int j = slot_to_n(rem, 0) & 511;
    float th = bp[(i * HALF + j) * BDEPTH + 0];
    c0[gid] = make_float2(cosf(th), sinf(th));
  }
  int g2 = gid - 4096;
  if (g2 >= 0 && g2 < 8192) {             // M8 row: thread per (i, gout, p)
    int i = g2 >> 10, gout = (g2 >> 6) & 15, p = g2 & 63;
    float v[8];
#pragma unroll
    for (int k = 0; k < 8; ++k) v[k] = (k == (gout & 7)) ? 1.f : 0.f;
    // row gout of S3*S2*S1: apply S3^T, S2^T, S1^T to e_{gout&7}
#pragma unroll
    for (int d = 3; d >= 1; --d) {
      const int mb = 1 << (3 - d);        // d3->1, d2->2, d1->4
#pragma unroll
      for (int glow = 0; glow < 8; ++glow) if (!(glow & mb)) {
        int slot = ((gout & 8) + glow) * 64 + p;       // bit(9-d)=0 element
        int n = slot_to_n(slot, d); int j = n & 511;
        float th = bp[(i * HALF + j) * BDEPTH + d];
        float c = cosf(th), s = sinf(th);
        float x0 = v[glow], x1 = v[glow | mb];
        v[glow]      = c * x0 - s * x1;   // transposed rotation
        v[glow | mb] = s * x0 + c * x1;
      }
    }
#pragma unroll
    for (int k = 0; k < 8; ++k)
      M8[(((i * 16 + gout) * 8 + k) * 64) + p] = v[k];  // [i][gout][g''][p]
  }
  int g3 = g2 - 8192;
  if (g3 >= 0 && g3 < (DEPTH - 1) * NQ * HALF) {        // qt (validated)
    int w = g3 & 511;
    int mi = (g3 >> 9) % NQ;
    int i = g3 / (NQ * HALF);
    int m = mi + 2;
    const float* cf = sc + (i * HALF + w) * SPLINE_DIM;
    double cc0 = cf[mi], cc1 = cf[mi + 1], cc2 = cf[mi + 2];
    double tm1 = d_T[m - 1], tm = d_T[m], tp1 = d_T[m + 1], tp2 = d_T[m + 2];
    double hh = tp1 - tm;
    double us[3] = { 0.0, 0.5 * hh, 0.75 * hh };
    double y[3];
#pragma unroll
    for (int k = 0; k < 3; ++k) {
      double x = tm + us[k];
      double left1 = x - tm, right1 = tp1 - x, left2 = x - tm1, right2 = tp2 - x;
      double inv1 = 1.0 / (tp1 - tm);
      double N0 = right1 * inv1, N1 = left1 * inv1;
      double temp0 = N0 / (tp1 - tm1);
      double B0 = right1 * temp0;
      double saved = left2 * temp0;
      double temp1 = N1 / (tp2 - tm);
      double B1 = right2 * temp1 + saved;
      double B2 = left1 * temp1;
      y[k] = cc0 * B0 + cc1 * B1 + cc2 * B2;
    }
    double d1 = y[1] - y[0], d2 = y[2] - y[0];
    double u1 = us[1], u2 = us[2];
    double det = u1 * u2 * (u2 - u1);
    double Bq = (d1 * u2 * u2 - d2 * u1 * u1) / det;
    double Cq = (d2 * u1 - d1 * u2) / det;
    qt[g3] = make_float4((float)y[0], (float)Bq, (float)Cq, (float)tm);
  }
}

// ---------------------------------------------------------------------------
// prepG: compose steps 4-9 into dense 64x64 orthogonal G per (layer, group),
// stored bf16 row-major [w'][w]. One wave per (i,g); column-at-a-time via the
// validated LSTEP shuffle-rotation form.
// ---------------------------------------------------------------------------
__global__ void prepG(const float* __restrict__ bp, unsigned short* __restrict__ Gt) {
  int ig = blockIdx.x;                   // i*16 + g
  int i = ig >> 4, g = ig & 15;
  int lane = threadIdx.x;
  int slot = g * 64 + lane;
  float cc[6], ssg[6];
#pragma unroll
  for (int d = 4; d <= 9; ++d) {
    int n = slot_to_n(slot, d); int j = n & 511;
    float th = bp[(i * HALF + j) * BDEPTH + d];
    float c = cosf(th), s = sinf(th);
    cc[d - 4] = c; ssg[d - 4] = (n & 512) ? -s : s;
  }
  for (int w = 0; w < 64; ++w) {
    float v = (lane == w) ? 1.f : 0.f;
#pragma unroll
    for (int d = 4; d <= 9; ++d) {
      float p = __shfl_xor(v, 1 << (9 - d), 64);
      v = cc[d - 4] * v + ssg[d - 4] * p;
    }
    Gt[(ig * 64 + lane) * 64 + w] = f2bf(v);   // row=w'(lane), col=w
  }
}

// Quadratic spline activation (validated R3+): interval-find + 1 load + 2 fma.
__device__ __forceinline__ float qspline(float x, const float4* __restrict__ qL, int w) {
  x = fminf(fmaxf(x, -8.0f), 7.9999990f);
  float ax = fabsf(x);
  unsigned bits = __float_as_uint(ax);
  int e = (int)(bits >> 23) - 127;
  int ce = e + ((bits & 0x7fffffu) ? 1 : 0);
  int m = (x > 0.f) ? (17 + e) : (5 - ce);
  m = (ax < 0.03125f) ? ((x < 0.f) ? 10 : 11) : m;
  float4 qc = qL[(m - 2) * HALF + w];
  float u = x - qc.w;
  return fmaf(u, fmaf(u, qc.z, qc.y), qc.x);
}

// ---------------------------------------------------------------------------
// fwd: 256 blocks x 512 thr. Block = 16 batch rows; wave wv owns groups
// {wv, wv+8}. Per layer: step0 (reg-local rotation) -> M8 8x8 group-mix
// (LDS exchange, class-sequential, bank-conflict-free stride-12) ->
// steps 4-9 as bf16 MFMA vs precomposed G (A-frags direct from registers,
// B-frags 16B contiguous from L2) -> D->A transpose (wave-local LDS slab,
// stride 68) -> spline (reg-local pairs G=1 -> G=0).
// ---------------------------------------------------------------------------
__global__ __launch_bounds__(512, 2) void fwd(
    const float* __restrict__ X, const float2* __restrict__ c0,
    const float* __restrict__ M8, const unsigned short* __restrict__ Gt,
    const float4* __restrict__ qt, float* __restrict__ out) {
  __shared__ float exch[12288];   // 48 KB: 16 segs * 768 (=64*12); tp slabs reuse it
  int tid = threadIdx.x, lane = tid & 63, wv = tid >> 6;
  int b = lane & 15, h = lane >> 4;
  int row = blockIdx.x * 16 + b;
  int hb12 = (h * 16 + b) * 12;

  float s[2][2][8];
#pragma unroll
  for (int G = 0; G < 2; ++G)
#pragma unroll
    for (int sl = 0; sl < 2; ++sl) {
      int w0 = (wv + G * 8) * 64 + sl * 32 + h * 8;
      if (w0 < NIN) {
        float4 a = *(const float4*)&X[(long)row * NIN + w0];
        float4 c = *(const float4*)&X[(long)row * NIN + w0 + 4];
        s[G][sl][0] = a.x; s[G][sl][1] = a.y; s[G][sl][2] = a.z; s[G][sl][3] = a.w;
        s[G][sl][4] = c.x; s[G][sl][5] = c.y; s[G][sl][6] = c.z; s[G][sl][7] = c.w;
      } else {
#pragma unroll
        for (int j = 0; j < 8; ++j) s[G][sl][j] = 0.f;
      }
    }

#pragma unroll 1
  for (int i = 0; i < DEPTH; ++i) {
    // ---- step 0: pair (g, g+8) rotation, register-local
    const float4* c0q = (const float4*)(c0 + i * 512 + wv * 64);
#pragma unroll
    for (int sl = 0; sl < 2; ++sl)
#pragma unroll
      for (int jj = 0; jj < 4; ++jj) {
        float4 cs2 = c0q[sl * 16 + h * 4 + jj];
        float a0 = s[0][sl][2 * jj], b0 = s[1][sl][2 * jj];
        s[0][sl][2 * jj] = fmaf(a0, cs2.x, b0 * cs2.y);
        s[1][sl][2 * jj] = fmaf(b0, cs2.x, -(a0 * cs2.y));
        float a1 = s[0][sl][2 * jj + 1], b1 = s[1][sl][2 * jj + 1];
        s[0][sl][2 * jj + 1] = fmaf(a1, cs2.z, b1 * cs2.w);
        s[1][sl][2 * jj + 1] = fmaf(b1, cs2.z, -(a1 * cs2.w));
      }

    // ---- steps 1-3: M8 8x8 group mix, class G sequential through exch
    float ns[2][2][8];
#pragma unroll
    for (int G = 0; G < 2; ++G) {
      int gout = wv + G * 8;
#pragma unroll
      for (int sl = 0; sl < 2; ++sl) {
        float* e = &exch[(wv * 2 + sl) * 768 + hb12];
        *(float4*)e = make_float4(s[G][sl][0], s[G][sl][1], s[G][sl][2], s[G][sl][3]);
        *(float4*)(e + 4) = make_float4(s[G][sl][4], s[G][sl][5], s[G][sl][6], s[G][sl][7]);
      }
      __syncthreads();
#pragma unroll
      for (int sl = 0; sl < 2; ++sl) {
#pragma unroll
        for (int j = 0; j < 8; ++j) ns[G][sl][j] = 0.f;
#pragma unroll
        for (int gp = 0; gp < 8; ++gp) {
          const float* cp = M8 + (((i * 16 + gout) * 8 + gp) * 64) + sl * 32 + h * 8;
          const float* e = &exch[(gp * 2 + sl) * 768 + hb12];
          float4 ca = *(const float4*)cp, cb = *(const float4*)(cp + 4);
          float4 ea = *(const float4*)e, eb = *(const float4*)(e + 4);
          ns[G][sl][0] = fmaf(ca.x, ea.x, ns[G][sl][0]);
          ns[G][sl][1] = fmaf(ca.y, ea.y, ns[G][sl][1]);
          ns[G][sl][2] = fmaf(ca.z, ea.z, ns[G][sl][2]);
          ns[G][sl][3] = fmaf(ca.w, ea.w, ns[G][sl][3]);
          ns[G][sl][4] = fmaf(cb.x, eb.x, ns[G][sl][4]);
          ns[G][sl][5] = fmaf(cb.y, eb.y, ns[G][sl][5]);
          ns[G][sl][6] = fmaf(cb.z, eb.z, ns[G][sl][6]);
          ns[G][sl][7] = fmaf(cb.w, eb.w, ns[G][sl][7]);
        }
      }
      __syncthreads();   // class reads done -> region reusable
    }
#pragma unroll
    for (int G = 0; G < 2; ++G)
#pragma unroll
      for (int sl = 0; sl < 2; ++sl)
#pragma unroll
        for (int j = 0; j < 8; ++j) s[G][sl][j] = ns[G][sl][j];

    // ---- steps 4-9: MFMA vs precomposed G, then D->A transpose via tp slab
    float* tp = exch + wv * 1088;   // 16 x 68
#pragma unroll
    for (int G = 0; G < 2; ++G) {
      int g = wv + G * 8;
      union { bf16x8 v; unsigned short u[8]; } A0, A1;
#pragma unroll
      for (int j = 0; j < 8; ++j) { A0.u[j] = f2bf(s[G][0][j]); A1.u[j] = f2bf(s[G][1][j]); }
      const unsigned short* GB = Gt + (long)((i * 16 + g) * 64) * 64;
#pragma unroll
      for (int t = 0; t < 4; ++t) {
        bf16x8 B0 = *(const bf16x8*)(GB + (t * 16 + b) * 64 + h * 8);
        bf16x8 B1 = *(const bf16x8*)(GB + (t * 16 + b) * 64 + 32 + h * 8);
        f32x4 acc = {0.f, 0.f, 0.f, 0.f};
        acc = __builtin_amdgcn_mfma_f32_16x16x32_bf16(A0.v, B0, acc, 0, 0, 0);
        acc = __builtin_amdgcn_mfma_f32_16x16x32_bf16(A1.v, B1, acc, 0, 0, 0);
#pragma unroll
        for (int q = 0; q < 4; ++q) tp[(h * 4 + q) * 68 + t * 16 + b] = acc[q];
      }
#pragma unroll
      for (int sl = 0; sl < 2; ++sl) {
        float4 r0 = *(const float4*)&tp[b * 68 + sl * 32 + h * 8];
        float4 r1 = *(const float4*)&tp[b * 68 + sl * 32 + h * 8 + 4];
        s[G][sl][0] = r0.x; s[G][sl][1] = r0.y; s[G][sl][2] = r0.z; s[G][sl][3] = r0.w;
        s[G][sl][4] = r1.x; s[G][sl][5] = r1.y; s[G][sl][6] = r1.z; s[G][sl][7] = r1.w;
      }
    }

    // ---- spline: X0 (G=0) += act(X1 (G=1)), register-local pairs
    if (i != DEPTH - 1) {
      const float4* qL = qt + i * (NQ * HALF);
#pragma unroll
      for (int sl = 0; sl < 2; ++sl)
#pragma unroll
        for (int j = 0; j < 8; ++j) {
          int widx = wv * 64 + sl * 32 + h * 8 + j;
          s[0][sl][j] += qspline(s[1][sl][j], qL, widx);
        }
    }
    __syncthreads();   // tp reads done before next layer's exch writes
  }

  // ---- store
#pragma unroll
  for (int G = 0; G < 2; ++G)
#pragma unroll
    for (int sl = 0; sl < 2; ++sl) {
      int w0 = (wv + G * 8) * 64 + sl * 32 + h * 8;
      if (w0 < NIN) {
        *(float4*)&out[(long)row * NIN + w0] =
            make_float4(s[G][sl][0], s[G][sl][1], s[G][sl][2], s[G][sl][3]);
        *(float4*)&out[(long)row * NIN + w0 + 4] =
            make_float4(s[G][sl][4], s[G][sl][5], s[G][sl][6], s[G][sl][7]);
      }
    }
}

extern "C" void kernel_launch(void* const* d_in, const int* in_sizes, int n_in,
                              void* d_out, int out_size, void* d_ws, size_t ws_size,
                              hipStream_t stream) {
  const float* X  = (const float*)d_in[0];
  const float* bp = (const float*)d_in[1];   // [8,512,10]
  const float* sc = (const float*)d_in[2];   // [7,512,20]
  float* out = (float*)d_out;

  char* ws = (char*)d_ws;
  unsigned short* Gt = (unsigned short*)ws;                       // 1,048,576 B
  float* M8 = (float*)(ws + 1048576);                             //   262,144 B
  float2* c0 = (float2*)(ws + 1048576 + 262144);                  //    32,768 B
  float4* qt = (float4*)(ws + 1048576 + 262144 + 32768);          // 1,032,192 B

  int prepA_threads = 4096 + 8192 + (DEPTH - 1) * NQ * HALF;      // 76,800
  prepA<<<(prepA_threads + 255) / 256, 256, 0, stream>>>(bp, sc, c0, M8, qt);
  prepG<<<DEPTH * 16, 64, 0, stream>>>(bp, Gt);
  fwd<<<BATCH / 16, 512, 0, stream>>>(X, c0, M8, Gt, qt, out);
}

// Round 11
// 107.160 us; speedup vs baseline: 1.1229x; 1.1229x over previous
//
#include <hip/hip_runtime.h>

#define DEPTH 8
#define BDEPTH 10
#define BATCH 4096
#define NIN 784
#define HALF 512
#define SPLINE_DIM 20
#define NQ 18

typedef __attribute__((ext_vector_type(8))) short bf16x8;
typedef __attribute__((ext_vector_type(4))) float f32x4;

__device__ float d_T[23] = {
  -8.f, -8.f, -8.f, -4.f, -2.f, -1.f, -0.5f, -0.25f, -0.125f, -0.0625f,
  -0.03125f, 0.f, 0.03125f, 0.0625f, 0.125f, 0.25f, 0.5f, 1.f, 2.f, 4.f,
  8.f, 8.f, 8.f };

// logical index n of slot at step d: n bit b = slot bit (b-d) mod 10  (validated R1-R10)
__device__ __forceinline__ int slot_to_n(int slot, int d) {
  int n = 0;
#pragma unroll
  for (int bb = 0; bb < 10; ++bb) { int src = bb - d; if (src < 0) src += 10; n |= ((slot >> src) & 1) << bb; }
  return n;
}

__device__ __forceinline__ unsigned short f2bf(float x) {  // RNE f32->bf16
  unsigned u = __float_as_uint(x);
  unsigned r = (u + 0x7fffu + ((u >> 16) & 1u)) >> 16;
  return (unsigned short)r;
}

// ---------------------------------------------------------------------------
// prepA (IDENTICAL to R10, validated): c0 step-0 rotations, M8 composed steps
// 1-3, qt per-interval quadratic spline.
// ---------------------------------------------------------------------------
__global__ void prepA(const float* __restrict__ bp, const float* __restrict__ sc,
                      float2* __restrict__ c0, float* __restrict__ M8,
                      float4* __restrict__ qt) {
  int gid = blockIdx.x * 256 + threadIdx.x;
  if (gid < 4096) {
    int i = gid >> 9, rem = gid & 511;
    int j = slot_to_n(rem, 0) & 511;
    float th = bp[(i * HALF + j) * BDEPTH + 0];
    c0[gid] = make_float2(cosf(th), sinf(th));
  }
  int g2 = gid - 4096;
  if (g2 >= 0 && g2 < 8192) {
    int i = g2 >> 10, gout = (g2 >> 6) & 15, p = g2 & 63;
    float v[8];
#pragma unroll
    for (int k = 0; k < 8; ++k) v[k] = (k == (gout & 7)) ? 1.f : 0.f;
#pragma unroll
    for (int d = 3; d >= 1; --d) {
      const int mb = 1 << (3 - d);
#pragma unroll
      for (int glow = 0; glow < 8; ++glow) if (!(glow & mb)) {
        int slot = ((gout & 8) + glow) * 64 + p;
        int n = slot_to_n(slot, d); int j = n & 511;
        float th = bp[(i * HALF + j) * BDEPTH + d];
        float c = cosf(th), s = sinf(th);
        float x0 = v[glow], x1 = v[glow | mb];
        v[glow]      = c * x0 - s * x1;
        v[glow | mb] = s * x0 + c * x1;
      }
    }
#pragma unroll
    for (int k = 0; k < 8; ++k)
      M8[(((i * 16 + gout) * 8 + k) * 64) + p] = v[k];
  }
  int g3 = g2 - 8192;
  if (g3 >= 0 && g3 < (DEPTH - 1) * NQ * HALF) {
    int w = g3 & 511;
    int mi = (g3 >> 9) % NQ;
    int i = g3 / (NQ * HALF);
    int m = mi + 2;
    const float* cf = sc + (i * HALF + w) * SPLINE_DIM;
    double cc0 = cf[mi], cc1 = cf[mi + 1], cc2 = cf[mi + 2];
    double tm1 = d_T[m - 1], tm = d_T[m], tp1 = d_T[m + 1], tp2 = d_T[m + 2];
    double hh = tp1 - tm;
    double us[3] = { 0.0, 0.5 * hh, 0.75 * hh };
    double y[3];
#pragma unroll
    for (int k = 0; k < 3; ++k) {
      double x = tm + us[k];
      double left1 = x - tm, right1 = tp1 - x, left2 = x - tm1, right2 = tp2 - x;
      double inv1 = 1.0 / (tp1 - tm);
      double N0 = right1 * inv1, N1 = left1 * inv1;
      double temp0 = N0 / (tp1 - tm1);
      double B0 = right1 * temp0;
      double saved = left2 * temp0;
      double temp1 = N1 / (tp2 - tm);
      double B1 = right2 * temp1 + saved;
      double B2 = left1 * temp1;
      y[k] = cc0 * B0 + cc1 * B1 + cc2 * B2;
    }
    double d1 = y[1] - y[0], d2 = y[2] - y[0];
    double u1 = us[1], u2 = us[2];
    double det = u1 * u2 * (u2 - u1);
    double Bq = (d1 * u2 * u2 - d2 * u1 * u1) / det;
    double Cq = (d2 * u1 - d1 * u2) / det;
    qt[g3] = make_float4((float)y[0], (float)Bq, (float)Cq, (float)tm);
  }
}

// ---------------------------------------------------------------------------
// prepG (IDENTICAL to R10, validated): steps 4-9 composed to 64x64 bf16 G.
// ---------------------------------------------------------------------------
__global__ void prepG(const float* __restrict__ bp, unsigned short* __restrict__ Gt) {
  int ig = blockIdx.x;
  int i = ig >> 4, g = ig & 15;
  int lane = threadIdx.x;
  int slot = g * 64 + lane;
  float cc[6], ssg[6];
#pragma unroll
  for (int d = 4; d <= 9; ++d) {
    int n = slot_to_n(slot, d); int j = n & 511;
    float th = bp[(i * HALF + j) * BDEPTH + d];
    float c = cosf(th), s = sinf(th);
    cc[d - 4] = c; ssg[d - 4] = (n & 512) ? -s : s;
  }
  for (int w = 0; w < 64; ++w) {
    float v = (lane == w) ? 1.f : 0.f;
#pragma unroll
    for (int d = 4; d <= 9; ++d) {
      float p = __shfl_xor(v, 1 << (9 - d), 64);
      v = cc[d - 4] * v + ssg[d - 4] * p;
    }
    Gt[(ig * 64 + lane) * 64 + w] = f2bf(v);
  }
}

// Quadratic spline activation (validated R3+).
__device__ __forceinline__ float qspline(float x, const float4* __restrict__ qL, int w) {
  x = fminf(fmaxf(x, -8.0f), 7.9999990f);
  float ax = fabsf(x);
  unsigned bits = __float_as_uint(ax);
  int e = (int)(bits >> 23) - 127;
  int ce = e + ((bits & 0x7fffffu) ? 1 : 0);
  int m = (x > 0.f) ? (17 + e) : (5 - ce);
  m = (ax < 0.03125f) ? ((x < 0.f) ? 10 : 11) : m;
  float4 qc = qL[(m - 2) * HALF + w];
  float u = x - qc.w;
  return fmaf(u, fmaf(u, qc.z, qc.y), qc.x);
}

// ---------------------------------------------------------------------------
// fwd: 256 blocks x 512 thr, block = 16 batch rows, wave wv owns groups
// {wv, wv+8}. State lives in MFMA D-layout across layers:
//   lane (b=lane&15, h=lane>>4), acc[c][t][q] = elem(row r=h*4+q, w'=g*64+t*16+b).
// Per layer: step0 (reg-local pair rot) -> ONE LDS exchange (write D-indexed
// scalar, read A-indexed float4 with XOR swizzle p^=((r&7)<<2); 2 barriers) +
// M8 mix (VALU, coefficients identical to R10) -> cvt_pk to bf16 A-frags ->
// 16 MFMA vs precomposed G (B-frags prefetched at layer top) -> spline
// (reg-local in D-layout). No transpose phase, no serialized classes.
// ---------------------------------------------------------------------------
__global__ __launch_bounds__(512) void fwd(
    const float* __restrict__ X, const float2* __restrict__ c0,
    const float* __restrict__ M8, const unsigned short* __restrict__ Gt,
    const float4* __restrict__ qt, float* __restrict__ out) {
  __shared__ __align__(16) float exch[16 * 16 * 64];   // 64 KB [g][r][p^swz(r)]
  int tid = threadIdx.x, lane = tid & 63, wv = tid >> 4 >> 2;  // wv = tid>>6
  int b = lane & 15, h = lane >> 4;
  const long rowbase = (long)blockIdx.x * 16;

  // ---- initial load straight into D-layout (quarter-coalesced b32)
  f32x4 acc[2][4];
#pragma unroll
  for (int c = 0; c < 2; ++c)
#pragma unroll
    for (int t = 0; t < 4; ++t) {
      int w = (wv + c * 8) * 64 + t * 16 + b;
      bool in = (w < NIN);
#pragma unroll
      for (int q = 0; q < 4; ++q)
        acc[c][t][q] = in ? X[(rowbase + h * 4 + q) * NIN + w] : 0.f;
    }

  // c0 for layer 0
  float2 c0v[4];
#pragma unroll
  for (int t = 0; t < 4; ++t) c0v[t] = c0[wv * 64 + t * 16 + b];

#pragma unroll 1
  for (int i = 0; i < DEPTH; ++i) {
    // ---- prefetch this layer's B-fragments (first use ~800cy later)
    bf16x8 Bf[2][4][2];
#pragma unroll
    for (int c = 0; c < 2; ++c)
#pragma unroll
      for (int t = 0; t < 4; ++t)
#pragma unroll
        for (int hf = 0; hf < 2; ++hf)
          Bf[c][t][hf] = *(const bf16x8*)(Gt +
              (long)(((i * 16 + wv + c * 8) * 64 + t * 16 + b)) * 64 + hf * 32 + h * 8);

    // ---- step 0: rotate (g, g+8) pairs, register-local in D-layout
#pragma unroll
    for (int t = 0; t < 4; ++t) {
      float cc = c0v[t].x, ss = c0v[t].y;
#pragma unroll
      for (int q = 0; q < 4; ++q) {
        float a0 = acc[0][t][q], a1 = acc[1][t][q];
        acc[0][t][q] = fmaf(a0, cc, a1 * ss);
        acc[1][t][q] = fmaf(a1, cc, -(a0 * ss));
      }
    }
    // prefetch c0 for next layer
    float2 c0n[4];
    {
      int ip = (i < DEPTH - 1) ? i + 1 : i;
#pragma unroll
      for (int t = 0; t < 4; ++t) c0n[t] = c0[ip * 512 + wv * 64 + t * 16 + b];
    }

    // ---- exchange write: D-indexed scalar b32, swizzled (bank-free)
#pragma unroll
    for (int c = 0; c < 2; ++c)
#pragma unroll
      for (int t = 0; t < 4; ++t)
#pragma unroll
        for (int q = 0; q < 4; ++q) {
          int r = h * 4 + q;
          int p = t * 16 + b;
          exch[((wv + c * 8) * 16 + r) * 64 + (p ^ ((r & 7) << 2))] = acc[c][t][q];
        }
    __syncthreads();

    // ---- M8 mix at A-layout positions (r=b, p=sl*32+h*8+j)
    float ns[2][2][8];
#pragma unroll
    for (int c = 0; c < 2; ++c)
#pragma unroll
      for (int sl = 0; sl < 2; ++sl)
#pragma unroll
        for (int j = 0; j < 8; ++j) ns[c][sl][j] = 0.f;
    int swz = (b & 7) << 2;
#pragma unroll
    for (int c = 0; c < 2; ++c)
#pragma unroll
      for (int k = 0; k < 8; ++k) {
        const float* cp = M8 + (((i * 16 + wv + c * 8) * 8 + k) * 64) + h * 8;
        int gb = ((c * 8 + k) * 16 + b) * 64;
#pragma unroll
        for (int sl = 0; sl < 2; ++sl) {
          float4 ca = *(const float4*)(cp + sl * 32);
          float4 cb = *(const float4*)(cp + sl * 32 + 4);
          float4 ea = *(const float4*)&exch[gb + ((sl * 32 + h * 8 + 0) ^ swz)];
          float4 eb = *(const float4*)&exch[gb + ((sl * 32 + h * 8 + 4) ^ swz)];
          ns[c][sl][0] = fmaf(ca.x, ea.x, ns[c][sl][0]);
          ns[c][sl][1] = fmaf(ca.y, ea.y, ns[c][sl][1]);
          ns[c][sl][2] = fmaf(ca.z, ea.z, ns[c][sl][2]);
          ns[c][sl][3] = fmaf(ca.w, ea.w, ns[c][sl][3]);
          ns[c][sl][4] = fmaf(cb.x, eb.x, ns[c][sl][4]);
          ns[c][sl][5] = fmaf(cb.y, eb.y, ns[c][sl][5]);
          ns[c][sl][6] = fmaf(cb.z, eb.z, ns[c][sl][6]);
          ns[c][sl][7] = fmaf(cb.w, eb.w, ns[c][sl][7]);
        }
      }
    __syncthreads();   // all reads done; next layer's writes may proceed

    // ---- cvt to bf16 A-frags (v_cvt_pk_bf16_f32)
    union Au { bf16x8 v; unsigned w[4]; } Afr[2][2];
#pragma unroll
    for (int c = 0; c < 2; ++c)
#pragma unroll
      for (int sl = 0; sl < 2; ++sl)
#pragma unroll
        for (int m = 0; m < 4; ++m)
          asm("v_cvt_pk_bf16_f32 %0, %1, %2"
              : "=v"(Afr[c][sl].w[m])
              : "v"(ns[c][sl][2 * m]), "v"(ns[c][sl][2 * m + 1]));

    // ---- steps 4-9: 16 MFMAs, output back into D-layout state
#pragma unroll
    for (int c = 0; c < 2; ++c)
#pragma unroll
      for (int t = 0; t < 4; ++t) {
        f32x4 a = {0.f, 0.f, 0.f, 0.f};
        a = __builtin_amdgcn_mfma_f32_16x16x32_bf16(Afr[c][0].v, Bf[c][t][0], a, 0, 0, 0);
        a = __builtin_amdgcn_mfma_f32_16x16x32_bf16(Afr[c][1].v, Bf[c][t][1], a, 0, 0, 0);
        acc[c][t] = a;
      }

    // ---- spline: X0 += act(X1), register-local in D-layout
    if (i != DEPTH - 1) {
      const float4* qL = qt + i * (NQ * HALF);
#pragma unroll
      for (int t = 0; t < 4; ++t) {
        int wq = wv * 64 + t * 16 + b;
#pragma unroll
        for (int q = 0; q < 4; ++q)
          acc[0][t][q] += qspline(acc[1][t][q], qL, wq);
      }
    }
#pragma unroll
    for (int t = 0; t < 4; ++t) c0v[t] = c0n[t];
  }

  // ---- store from D-layout (quarter-coalesced b32)
#pragma unroll
  for (int c = 0; c < 2; ++c)
#pragma unroll
    for (int t = 0; t < 4; ++t) {
      int w = (wv + c * 8) * 64 + t * 16 + b;
      if (w < NIN) {
#pragma unroll
        for (int q = 0; q < 4; ++q)
          out[(rowbase + h * 4 + q) * NIN + w] = acc[c][t][q];
      }
    }
}

extern "C" void kernel_launch(void* const* d_in, const int* in_sizes, int n_in,
                              void* d_out, int out_size, void* d_ws, size_t ws_size,
                              hipStream_t stream) {
  const float* X  = (const float*)d_in[0];
  const float* bp = (const float*)d_in[1];   // [8,512,10]
  const float* sc = (const float*)d_in[2];   // [7,512,20]
  float* out = (float*)d_out;

  char* ws = (char*)d_ws;
  unsigned short* Gt = (unsigned short*)ws;                       // 1,048,576 B
  float* M8 = (float*)(ws + 1048576);                             //   262,144 B
  float2* c0 = (float2*)(ws + 1048576 + 262144);                  //    32,768 B
  float4* qt = (float4*)(ws + 1048576 + 262144 + 32768);          // 1,032,192 B

  int prepA_threads = 4096 + 8192 + (DEPTH - 1) * NQ * HALF;      // 76,800
  prepA<<<(prepA_threads + 255) / 256, 256, 0, stream>>>(bp, sc, c0, M8, qt);
  prepG<<<DEPTH * 16, 64, 0, stream>>>(bp, Gt);
  fwd<<<BATCH / 16, 512, 0, stream>>>(X, c0, M8, Gt, qt, out);
}

// Round 12
// 104.386 us; speedup vs baseline: 1.1527x; 1.0266x over previous
//
#include <hip/hip_runtime.h>

#define DEPTH 8
#define BDEPTH 10
#define BATCH 4096
#define NIN 784
#define HALF 512
#define SPLINE_DIM 20
#define NQ 18

typedef __attribute__((ext_vector_type(8))) short bf16x8;
typedef __attribute__((ext_vector_type(4))) float f32x4;

__device__ float d_T[23] = {
  -8.f, -8.f, -8.f, -4.f, -2.f, -1.f, -0.5f, -0.25f, -0.125f, -0.0625f,
  -0.03125f, 0.f, 0.03125f, 0.0625f, 0.125f, 0.25f, 0.5f, 1.f, 2.f, 4.f,
  8.f, 8.f, 8.f };

// logical index n of slot at step d: n bit b = slot bit (b-d) mod 10  (validated R1-R11)
__device__ __forceinline__ int slot_to_n(int slot, int d) {
  int n = 0;
#pragma unroll
  for (int bb = 0; bb < 10; ++bb) { int src = bb - d; if (src < 0) src += 10; n |= ((slot >> src) & 1) << bb; }
  return n;
}

__device__ __forceinline__ unsigned short f2bf(float x) {  // RNE f32->bf16
  unsigned u = __float_as_uint(x);
  unsigned r = (u + 0x7fffu + ((u >> 16) & 1u)) >> 16;
  return (unsigned short)r;
}

// ---------------------------------------------------------------------------
// prep (merged prepG + prepA, all ranges 256-aligned so each block is
// single-range; prepG range [0,8192) is wave-aligned for its shuffles).
//   [0,8192):      Gt  -- steps 4-9 composed to 64x64 bf16 G per (i,g)
//   [8192,12288):  c0  -- step-0 rotations
//   [12288,20480): M8  -- composed steps 1-3 (8x8 per (i,gout,p))
//   [20480,84992): qt  -- per-interval quadratic spline coefficients
// All bodies byte-identical math to the R10/R11 validated versions.
// ---------------------------------------------------------------------------
__global__ void prep(const float* __restrict__ bp, const float* __restrict__ sc,
                     float2* __restrict__ c0, float* __restrict__ M8,
                     unsigned short* __restrict__ Gt, float4* __restrict__ qt) {
  int gid = blockIdx.x * 256 + threadIdx.x;
  if (gid < 8192) {                       // ---- Gt (prepG)
    int ig = gid >> 6;                    // i*16 + g
    int i = ig >> 4, g = ig & 15;
    int lane = gid & 63;
    int slot = g * 64 + lane;
    float cc[6], ssg[6];
#pragma unroll
    for (int d = 4; d <= 9; ++d) {
      int n = slot_to_n(slot, d); int j = n & 511;
      float th = bp[(i * HALF + j) * BDEPTH + d];
      float c = cosf(th), s = sinf(th);
      cc[d - 4] = c; ssg[d - 4] = (n & 512) ? -s : s;
    }
    for (int w = 0; w < 64; ++w) {
      float v = (lane == w) ? 1.f : 0.f;
#pragma unroll
      for (int d = 4; d <= 9; ++d) {
        float p = __shfl_xor(v, 1 << (9 - d), 64);
        v = cc[d - 4] * v + ssg[d - 4] * p;
      }
      Gt[(ig * 64 + lane) * 64 + w] = f2bf(v);
    }
    return;
  }
  int gA = gid - 8192;
  if (gA >= 0 && gA < 4096) {             // ---- c0
    int i = gA >> 9, rem = gA & 511;
    int j = slot_to_n(rem, 0) & 511;
    float th = bp[(i * HALF + j) * BDEPTH + 0];
    c0[gA] = make_float2(cosf(th), sinf(th));
    return;
  }
  int g2 = gA - 4096;
  if (g2 >= 0 && g2 < 8192) {             // ---- M8
    int i = g2 >> 10, gout = (g2 >> 6) & 15, p = g2 & 63;
    float v[8];
#pragma unroll
    for (int k = 0; k < 8; ++k) v[k] = (k == (gout & 7)) ? 1.f : 0.f;
#pragma unroll
    for (int d = 3; d >= 1; --d) {
      const int mb = 1 << (3 - d);
#pragma unroll
      for (int glow = 0; glow < 8; ++glow) if (!(glow & mb)) {
        int slot = ((gout & 8) + glow) * 64 + p;
        int n = slot_to_n(slot, d); int j = n & 511;
        float th = bp[(i * HALF + j) * BDEPTH + d];
        float c = cosf(th), s = sinf(th);
        float x0 = v[glow], x1 = v[glow | mb];
        v[glow]      = c * x0 - s * x1;
        v[glow | mb] = s * x0 + c * x1;
      }
    }
#pragma unroll
    for (int k = 0; k < 8; ++k)
      M8[(((i * 16 + gout) * 8 + k) * 64) + p] = v[k];
    return;
  }
  int g3 = g2 - 8192;
  if (g3 >= 0 && g3 < (DEPTH - 1) * NQ * HALF) {   // ---- qt
    int w = g3 & 511;
    int mi = (g3 >> 9) % NQ;
    int i = g3 / (NQ * HALF);
    int m = mi + 2;
    const float* cf = sc + (i * HALF + w) * SPLINE_DIM;
    double cc0 = cf[mi], cc1 = cf[mi + 1], cc2 = cf[mi + 2];
    double tm1 = d_T[m - 1], tm = d_T[m], tp1 = d_T[m + 1], tp2 = d_T[m + 2];
    double hh = tp1 - tm;
    double us[3] = { 0.0, 0.5 * hh, 0.75 * hh };
    double y[3];
#pragma unroll
    for (int k = 0; k < 3; ++k) {
      double x = tm + us[k];
      double left1 = x - tm, right1 = tp1 - x, left2 = x - tm1, right2 = tp2 - x;
      double inv1 = 1.0 / (tp1 - tm);
      double N0 = right1 * inv1, N1 = left1 * inv1;
      double temp0 = N0 / (tp1 - tm1);
      double B0 = right1 * temp0;
      double saved = left2 * temp0;
      double temp1 = N1 / (tp2 - tm);
      double B1 = right2 * temp1 + saved;
      double B2 = left1 * temp1;
      y[k] = cc0 * B0 + cc1 * B1 + cc2 * B2;
    }
    double d1 = y[1] - y[0], d2 = y[2] - y[0];
    double u1 = us[1], u2 = us[2];
    double det = u1 * u2 * (u2 - u1);
    double Bq = (d1 * u2 * u2 - d2 * u1 * u1) / det;
    double Cq = (d2 * u1 - d1 * u2) / det;
    qt[g3] = make_float4((float)y[0], (float)Bq, (float)Cq, (float)tm);
  }
}

// Quadratic spline activation (validated R3+).
__device__ __forceinline__ float qspline(float x, const float4* __restrict__ qL, int w) {
  x = fminf(fmaxf(x, -8.0f), 7.9999990f);
  float ax = fabsf(x);
  unsigned bits = __float_as_uint(ax);
  int e = (int)(bits >> 23) - 127;
  int ce = e + ((bits & 0x7fffffu) ? 1 : 0);
  int m = (x > 0.f) ? (17 + e) : (5 - ce);
  m = (ax < 0.03125f) ? ((x < 0.f) ? 10 : 11) : m;
  float4 qc = qL[(m - 2) * HALF + w];
  float u = x - qc.w;
  return fmaf(u, fmaf(u, qc.z, qc.y), qc.x);
}

// ---------------------------------------------------------------------------
// fwd (structure = validated R11; dataflow identical). Changes vs R11:
//  * __launch_bounds__(512,1): grid pins us at 1 block/CU (8 waves), so up to
//    ~450 VGPRs are free -- lift the 124-reg squeeze that blocked load hoisting.
//  * M8 coefficients hand-staged into registers: CF0 (c=0, 32x float4) issued
//    BEFORE the exchange barrier; CF1 staged between the c=0 and c=1 fma
//    blocks. Their L2 latency hides under exchange + mix instead of
//    serializing inside the fma chains.
//  * Bf (G-matrix) fragments loaded after the mix (regs free by then),
//    consumed ~20 instrs later at the MFMAs.
// ---------------------------------------------------------------------------
__global__ __launch_bounds__(512, 1) void fwd(
    const float* __restrict__ X, const float2* __restrict__ c0,
    const float* __restrict__ M8, const unsigned short* __restrict__ Gt,
    const float4* __restrict__ qt, float* __restrict__ out) {
  __shared__ __align__(16) float exch[16 * 16 * 64];   // 64 KB [g][r][p^swz(r)]
  int tid = threadIdx.x, lane = tid & 63, wv = tid >> 6;
  int b = lane & 15, h = lane >> 4;
  const long rowbase = (long)blockIdx.x * 16;

  // ---- initial load straight into D-layout
  f32x4 acc[2][4];
#pragma unroll
  for (int c = 0; c < 2; ++c)
#pragma unroll
    for (int t = 0; t < 4; ++t) {
      int w = (wv + c * 8) * 64 + t * 16 + b;
      bool in = (w < NIN);
#pragma unroll
      for (int q = 0; q < 4; ++q)
        acc[c][t][q] = in ? X[(rowbase + h * 4 + q) * NIN + w] : 0.f;
    }

  float2 c0v[4];
#pragma unroll
  for (int t = 0; t < 4; ++t) c0v[t] = c0[wv * 64 + t * 16 + b];

#pragma unroll 1
  for (int i = 0; i < DEPTH; ++i) {
    // ---- step 0: rotate (g, g+8) pairs, register-local in D-layout
#pragma unroll
    for (int t = 0; t < 4; ++t) {
      float cc = c0v[t].x, ss = c0v[t].y;
#pragma unroll
      for (int q = 0; q < 4; ++q) {
        float a0 = acc[0][t][q], a1 = acc[1][t][q];
        acc[0][t][q] = fmaf(a0, cc, a1 * ss);
        acc[1][t][q] = fmaf(a1, cc, -(a0 * ss));
      }
    }
    // prefetch c0 for next layer
    float2 c0n[4];
    {
      int ip = (i < DEPTH - 1) ? i + 1 : i;
#pragma unroll
      for (int t = 0; t < 4; ++t) c0n[t] = c0[ip * 512 + wv * 64 + t * 16 + b];
    }

    // ---- stage c=0 mix coefficients NOW (latency hides under write+barrier)
    float4 CF0[8][4];
#pragma unroll
    for (int k = 0; k < 8; ++k) {
      const float* cp = M8 + (((i * 16 + wv) * 8 + k) * 64) + h * 8;
      CF0[k][0] = *(const float4*)cp;
      CF0[k][1] = *(const float4*)(cp + 4);
      CF0[k][2] = *(const float4*)(cp + 32);
      CF0[k][3] = *(const float4*)(cp + 36);
    }

    // ---- exchange write: D-indexed scalar b32, swizzled
#pragma unroll
    for (int c = 0; c < 2; ++c)
#pragma unroll
      for (int t = 0; t < 4; ++t)
#pragma unroll
        for (int q = 0; q < 4; ++q) {
          int r = h * 4 + q;
          int p = t * 16 + b;
          exch[((wv + c * 8) * 16 + r) * 64 + (p ^ ((r & 7) << 2))] = acc[c][t][q];
        }
    __syncthreads();

    // ---- M8 mix at A-layout positions (r=b, p=sl*32+h*8+j)
    float ns[2][2][8];
    int swz = (b & 7) << 2;
    // c = 0 (coeffs already in CF0)
#pragma unroll
    for (int sl = 0; sl < 2; ++sl)
#pragma unroll
      for (int j = 0; j < 8; ++j) ns[0][sl][j] = 0.f;
#pragma unroll
    for (int k = 0; k < 8; ++k) {
      int gb = (k * 16 + b) * 64;
#pragma unroll
      for (int sl = 0; sl < 2; ++sl) {
        float4 ca = CF0[k][sl * 2], cb = CF0[k][sl * 2 + 1];
        float4 ea = *(const float4*)&exch[gb + ((sl * 32 + h * 8 + 0) ^ swz)];
        float4 eb = *(const float4*)&exch[gb + ((sl * 32 + h * 8 + 4) ^ swz)];
        ns[0][sl][0] = fmaf(ca.x, ea.x, ns[0][sl][0]);
        ns[0][sl][1] = fmaf(ca.y, ea.y, ns[0][sl][1]);
        ns[0][sl][2] = fmaf(ca.z, ea.z, ns[0][sl][2]);
        ns[0][sl][3] = fmaf(ca.w, ea.w, ns[0][sl][3]);
        ns[0][sl][4] = fmaf(cb.x, eb.x, ns[0][sl][4]);
        ns[0][sl][5] = fmaf(cb.y, eb.y, ns[0][sl][5]);
        ns[0][sl][6] = fmaf(cb.z, eb.z, ns[0][sl][6]);
        ns[0][sl][7] = fmaf(cb.w, eb.w, ns[0][sl][7]);
      }
    }
    // stage c=1 coefficients (CF0 regs free), then mix c=1
    float4 CF1[8][4];
#pragma unroll
    for (int k = 0; k < 8; ++k) {
      const float* cp = M8 + (((i * 16 + wv + 8) * 8 + k) * 64) + h * 8;
      CF1[k][0] = *(const float4*)cp;
      CF1[k][1] = *(const float4*)(cp + 4);
      CF1[k][2] = *(const float4*)(cp + 32);
      CF1[k][3] = *(const float4*)(cp + 36);
    }
#pragma unroll
    for (int sl = 0; sl < 2; ++sl)
#pragma unroll
      for (int j = 0; j < 8; ++j) ns[1][sl][j] = 0.f;
#pragma unroll
    for (int k = 0; k < 8; ++k) {
      int gb = ((8 + k) * 16 + b) * 64;
#pragma unroll
      for (int sl = 0; sl < 2; ++sl) {
        float4 ca = CF1[k][sl * 2], cb = CF1[k][sl * 2 + 1];
        float4 ea = *(const float4*)&exch[gb + ((sl * 32 + h * 8 + 0) ^ swz)];
        float4 eb = *(const float4*)&exch[gb + ((sl * 32 + h * 8 + 4) ^ swz)];
        ns[1][sl][0] = fmaf(ca.x, ea.x, ns[1][sl][0]);
        ns[1][sl][1] = fmaf(ca.y, ea.y, ns[1][sl][1]);
        ns[1][sl][2] = fmaf(ca.z, ea.z, ns[1][sl][2]);
        ns[1][sl][3] = fmaf(ca.w, ea.w, ns[1][sl][3]);
        ns[1][sl][4] = fmaf(cb.x, eb.x, ns[1][sl][4]);
        ns[1][sl][5] = fmaf(cb.y, eb.y, ns[1][sl][5]);
        ns[1][sl][6] = fmaf(cb.z, eb.z, ns[1][sl][6]);
        ns[1][sl][7] = fmaf(cb.w, eb.w, ns[1][sl][7]);
      }
    }

    // ---- B-fragments for the MFMAs (loaded late: regs free, used ~20 instrs on)
    bf16x8 Bf[2][4][2];
#pragma unroll
    for (int c = 0; c < 2; ++c)
#pragma unroll
      for (int t = 0; t < 4; ++t)
#pragma unroll
        for (int hf = 0; hf < 2; ++hf)
          Bf[c][t][hf] = *(const bf16x8*)(Gt +
              (long)(((i * 16 + wv + c * 8) * 64 + t * 16 + b)) * 64 + hf * 32 + h * 8);

    __syncthreads();   // all exch reads done; next layer's writes may proceed

    // ---- cvt to bf16 A-frags
    union Au { bf16x8 v; unsigned w[4]; } Afr[2][2];
#pragma unroll
    for (int c = 0; c < 2; ++c)
#pragma unroll
      for (int sl = 0; sl < 2; ++sl)
#pragma unroll
        for (int m = 0; m < 4; ++m)
          asm("v_cvt_pk_bf16_f32 %0, %1, %2"
              : "=v"(Afr[c][sl].w[m])
              : "v"(ns[c][sl][2 * m]), "v"(ns[c][sl][2 * m + 1]));

    // ---- steps 4-9: 16 MFMAs
#pragma unroll
    for (int c = 0; c < 2; ++c)
#pragma unroll
      for (int t = 0; t < 4; ++t) {
        f32x4 a = {0.f, 0.f, 0.f, 0.f};
        a = __builtin_amdgcn_mfma_f32_16x16x32_bf16(Afr[c][0].v, Bf[c][t][0], a, 0, 0, 0);
        a = __builtin_amdgcn_mfma_f32_16x16x32_bf16(Afr[c][1].v, Bf[c][t][1], a, 0, 0, 0);
        acc[c][t] = a;
      }

    // ---- spline: X0 += act(X1), register-local in D-layout
    if (i != DEPTH - 1) {
      const float4* qL = qt + i * (NQ * HALF);
#pragma unroll
      for (int t = 0; t < 4; ++t) {
        int wq = wv * 64 + t * 16 + b;
#pragma unroll
        for (int q = 0; q < 4; ++q)
          acc[0][t][q] += qspline(acc[1][t][q], qL, wq);
      }
    }
#pragma unroll
    for (int t = 0; t < 4; ++t) c0v[t] = c0n[t];
  }

  // ---- store from D-layout
#pragma unroll
  for (int c = 0; c < 2; ++c)
#pragma unroll
    for (int t = 0; t < 4; ++t) {
      int w = (wv + c * 8) * 64 + t * 16 + b;
      if (w < NIN) {
#pragma unroll
        for (int q = 0; q < 4; ++q)
          out[(rowbase + h * 4 + q) * NIN + w] = acc[c][t][q];
      }
    }
}

extern "C" void kernel_launch(void* const* d_in, const int* in_sizes, int n_in,
                              void* d_out, int out_size, void* d_ws, size_t ws_size,
                              hipStream_t stream) {
  const float* X  = (const float*)d_in[0];
  const float* bp = (const float*)d_in[1];   // [8,512,10]
  const float* sc = (const float*)d_in[2];   // [7,512,20]
  float* out = (float*)d_out;

  char* ws = (char*)d_ws;
  unsigned short* Gt = (unsigned short*)ws;                       // 1,048,576 B
  float* M8 = (float*)(ws + 1048576);                             //   262,144 B
  float2* c0 = (float2*)(ws + 1048576 + 262144);                  //    32,768 B
  float4* qt = (float4*)(ws + 1048576 + 262144 + 32768);          // 1,032,192 B

  int prep_threads = 8192 + 4096 + 8192 + (DEPTH - 1) * NQ * HALF; // 84,992
  prep<<<(prep_threads + 255) / 256, 256, 0, stream>>>(bp, sc, c0, M8, Gt, qt);
  fwd<<<BATCH / 16, 512, 0, stream>>>(X, c0, M8, Gt, qt, out);
}

// Round 13
// 70.860 us; speedup vs baseline: 1.6981x; 1.4731x over previous
//
#include <hip/hip_runtime.h>

#define NIN 784
#define WIDTH 1024
#define HALF 512
#define DEPTH 8
#define BDEPTH 10
#define BATCH 4096
#define SPLINE_DIM 20
#define NQ 18   // knot intervals [t_m, t_m+1), m = 2..19

// Clamped knot vector T[23]: [-8]*3, +-2^k/32 ladder, 0, [8]*3
__device__ float d_T[23] = {
  -8.f, -8.f, -8.f, -4.f, -2.f, -1.f, -0.5f, -0.25f, -0.125f, -0.0625f,
  -0.03125f, 0.f, 0.03125f, 0.0625f, 0.125f, 0.25f, 0.5f, 1.f, 2.f, 4.f,
  8.f, 8.f, 8.f };

// ---------------------------------------------------------------------------
// Prep kernel (validated R3-R8): cs rotation tables + qt quadratic spline.
// ---------------------------------------------------------------------------
__global__ void prep_kernel(const float* __restrict__ bp,
                            const float* __restrict__ sc,
                            float2* __restrict__ cs,
                            float4* __restrict__ qt) {
  int gid = blockIdx.x * 256 + threadIdx.x;
  if (gid < DEPTH * BDEPTH * 1024) {
    int slot = gid & 1023;
    int d = (gid >> 10) % BDEPTH;
    int i = gid / (BDEPTH * 1024);
    int n = 0;
#pragma unroll
    for (int b = 0; b < 10; ++b) {
      int src = b - d; if (src < 0) src += 10;
      n |= ((slot >> src) & 1) << b;
    }
    int pj = n & 511;
    float theta = bp[(i * HALF + pj) * BDEPTH + d];
    float c = cosf(theta), s = sinf(theta);
    cs[gid] = make_float2(c, (n & 512) ? -s : s);
  }
  int gid2 = gid - DEPTH * BDEPTH * 1024;
  if (gid2 >= 0 && gid2 < (DEPTH - 1) * NQ * HALF) {
    int w = gid2 & 511;
    int mi = (gid2 >> 9) % NQ;
    int i = gid2 / (NQ * HALF);
    int m = mi + 2;
    const float* cf = sc + (i * HALF + w) * SPLINE_DIM;
    double c0 = cf[mi], c1 = cf[mi + 1], c2 = cf[mi + 2];
    double tm1 = d_T[m - 1], tm = d_T[m], tp1 = d_T[m + 1], tp2 = d_T[m + 2];
    double h = tp1 - tm;
    double us[3] = { 0.0, 0.5 * h, 0.75 * h };
    double y[3];
#pragma unroll
    for (int k = 0; k < 3; ++k) {
      double x = tm + us[k];
      double left1 = x - tm, right1 = tp1 - x, left2 = x - tm1, right2 = tp2 - x;
      double inv1 = 1.0 / (tp1 - tm);
      double N0 = right1 * inv1, N1 = left1 * inv1;
      double temp0 = N0 / (tp1 - tm1);
      double B0 = right1 * temp0;
      double saved = left2 * temp0;
      double temp1 = N1 / (tp2 - tm);
      double B1 = right2 * temp1 + saved;
      double B2 = left1 * temp1;
      y[k] = c0 * B0 + c1 * B1 + c2 * B2;
    }
    double d1 = y[1] - y[0], d2 = y[2] - y[0];
    double u1 = us[1], u2 = us[2];
    double det = u1 * u2 * (u2 - u1);
    double Bq = (d1 * u2 * u2 - d2 * u1 * u1) / det;
    double Cq = (d2 * u1 - d1 * u2) / det;
    qt[gid2] = make_float4((float)y[0], (float)Bq, (float)Cq, (float)tm);
  }
}

// ---------------------------------------------------------------------------
// Compile-time lane shuffles (validated): DPP xor1/2, ds_swizzle 4/8/16,
// bpermute for 32.
// ---------------------------------------------------------------------------
template <int M>
__device__ __forceinline__ float shfx(float x) {
  if constexpr (M == 1)
    return __int_as_float(__builtin_amdgcn_mov_dpp(__float_as_int(x), 0xB1, 0xF, 0xF, true));
  else if constexpr (M == 2)
    return __int_as_float(__builtin_amdgcn_mov_dpp(__float_as_int(x), 0x4E, 0xF, 0xF, true));
  else if constexpr (M == 4)
    return __int_as_float(__builtin_amdgcn_ds_swizzle(__float_as_int(x), 0x101F));
  else if constexpr (M == 8)
    return __int_as_float(__builtin_amdgcn_ds_swizzle(__float_as_int(x), 0x201F));
  else if constexpr (M == 16)
    return __int_as_float(__builtin_amdgcn_ds_swizzle(__float_as_int(x), 0x401F));
  else
    return __shfl_xor(x, 32, 64);
}

// Quadratic spline activation (validated R3+).
__device__ __forceinline__ float qspline(float x, const float4* __restrict__ qL, int w) {
  x = fminf(fmaxf(x, -8.0f), 7.9999990f);
  float ax = fabsf(x);
  unsigned bits = __float_as_uint(ax);
  int e = (int)(bits >> 23) - 127;
  int ce = e + ((bits & 0x7fffffu) ? 1 : 0);
  int m = (x > 0.f) ? (17 + e) : (5 - ce);
  m = (ax < 0.03125f) ? ((x < 0.f) ? 10 : 11) : m;
  float4 qc = qL[(m - 2) * HALF + w];
  float u = x - qc.w;
  return fmaf(u, fmaf(u, qc.z, qc.y), qc.x);
}

typedef __attribute__((address_space(3))) unsigned int lds_u32;
typedef __attribute__((address_space(1))) const unsigned int glb_u32;

// Async-stage one 5-step chunk (40 KB) into LDS buffer `dst` via
// global_load_lds (16B/lane DMA). 40 wave-segments of 1 KB; wave wv takes
// segments {k*8+wv}. LDS dest is wave-uniform base (+ lane*16 implicit) --
// usage verified correct in R9.
__device__ __forceinline__ void stage_async(const float2* __restrict__ src,
                                            float2* dst, int wv) {
#pragma unroll
  for (int k = 0; k < 5; ++k) {
    int seg = k * 8 + wv;
    const char* g = (const char*)src + seg * 1024 + (threadIdx.x & 63) * 16;
    char* l = (char*)dst + seg * 1024;
    __builtin_amdgcn_global_load_lds((glb_u32*)g, (lds_u32*)l, 16, 0, 0);
  }
}

// butterfly step dd<4 from LDS buffer P slot sl: partner = reg ^ (8>>dd), 2 rows
#define CSTEPL(P, sl, dd) do {                                                \
    const int _mr = 8 >> (dd);                                                \
    _Pragma("unroll") for (int r = 0; r < 16; ++r)                            \
      if ((r & _mr) == 0) {                                                   \
        float2 v = P[(sl) * 1024 + r * 64 + lane];                            \
        float a0 = s0[r], b0 = s0[r + _mr];                                   \
        s0[r]       = fmaf(a0, v.x, b0 * v.y);                                \
        s0[r + _mr] = fmaf(b0, v.x, -(a0 * v.y));                             \
        float a1 = s1[r], b1 = s1[r + _mr];                                   \
        s1[r]       = fmaf(a1, v.x, b1 * v.y);                                \
        s1[r + _mr] = fmaf(b1, v.x, -(a1 * v.y));                             \
      }                                                                       \
  } while (0)

// butterfly step dd>=4 from LDS buffer P slot sl: partner = lane ^ MM, 2 rows
#define LSTEPL(P, sl, MM) do {                                                \
    _Pragma("unroll") for (int r = 0; r < 16; ++r) {                          \
      float2 v = P[(sl) * 1024 + r * 64 + lane];                              \
      float p0 = shfx<MM>(s0[r]);                                             \
      float p1 = shfx<MM>(s1[r]);                                             \
      s0[r] = fmaf(s0[r], v.x, p0 * v.y);                                     \
      s1[r] = fmaf(s1[r], v.x, p1 * v.y);                                     \
    }                                                                         \
  } while (0)

// ---------------------------------------------------------------------------
// Main kernel: 256 blocks x 512 threads (8 waves), TWO rows per wave
// (16 rows/block). Exactly 1 block/CU, so the 80 KB double-buffer is free.
// vs R8: half the total staging traffic (shared by 16 rows instead of 8) and
// ASYNC staging -- next chunk's global_load_lds DMAs are issued before the
// current chunk's compute, waited with counted vmcnt(5) one phase later.
// Per-wave compute identical to the validated R7 macros.
// ---------------------------------------------------------------------------
__global__ __launch_bounds__(512, 1) void fwd_kernel(
    const float* __restrict__ X, const float2* __restrict__ cs,
    const float4* __restrict__ qt, float* __restrict__ out) {
  __shared__ float2 csA[5 * 1024];   // 40 KB
  __shared__ float2 csB[5 * 1024];   // 40 KB
  int tid = threadIdx.x;
  int lane = tid & 63;
  int wv = tid >> 6;                       // 0..7
  int row0 = blockIdx.x * 16 + wv * 2;

  const float* x0p = X + (long)row0 * NIN;
  const float* x1p = X + (long)(row0 + 1) * NIN;
  float s0[16], s1[16];
#pragma unroll
  for (int r = 0; r < 16; ++r) {
    int w = r * 64 + lane;
    bool in = (w < NIN);
    s0[r] = in ? x0p[w] : 0.f;
    s1[r] = in ? x1p[w] : 0.f;
  }

  // prologue: start DMA of layer 0 steps 0-4 into csA
  stage_async(cs, csA, wv);

#pragma unroll 1
  for (int i = 0; i < DEPTH; ++i) {
    const float2* csL = cs + i * (BDEPTH * 1024);

    __syncthreads();                               // csB free (prev layer consumed)
    stage_async(csL + 5 * 1024, csB, wv);          // issue steps 5-9 DMA
    asm volatile("s_waitcnt vmcnt(5)" ::: "memory"); // csA's 5 DMAs done
    __syncthreads();                               // all waves' csA DMAs landed
    CSTEPL(csA, 0, 0);
    CSTEPL(csA, 1, 1);
    CSTEPL(csA, 2, 2);
    CSTEPL(csA, 3, 3);
    LSTEPL(csA, 4, 32);

    __syncthreads();                               // csA free
    // issue next layer's steps 0-4 DMA (wrap at i=7: dummy, never read)
    stage_async(cs + ((i + 1) & 7) * (BDEPTH * 1024), csA, wv);
    asm volatile("s_waitcnt vmcnt(5)" ::: "memory"); // csB's 5 DMAs done
    __syncthreads();                               // all waves' csB DMAs landed
    LSTEPL(csB, 0, 16);
    LSTEPL(csB, 1, 8);
    LSTEPL(csB, 2, 4);
    LSTEPL(csB, 3, 2);
    LSTEPL(csB, 4, 1);

    if (i != DEPTH - 1) {
      const float4* qL = qt + i * (NQ * HALF);
#pragma unroll
      for (int r = 8; r < 16; ++r) {
        int w = ((r - 8) << 6) | lane;
        s0[r - 8] += qspline(s0[r], qL, w);
        s1[r - 8] += qspline(s1[r], qL, w);
      }
    }
  }

  float* o0 = out + (long)row0 * NIN;
  float* o1 = out + (long)(row0 + 1) * NIN;
#pragma unroll
  for (int r = 0; r < 13; ++r) {
    int w = r * 64 + lane;
    if (w < NIN) { o0[w] = s0[r]; o1[w] = s1[r]; }
  }
}

extern "C" void kernel_launch(void* const* d_in, const int* in_sizes, int n_in,
                              void* d_out, int out_size, void* d_ws, size_t ws_size,
                              hipStream_t stream) {
  const float* X  = (const float*)d_in[0];
  const float* bp = (const float*)d_in[1];   // [8,512,10]
  const float* sc = (const float*)d_in[2];   // [7,512,20]
  float* out = (float*)d_out;

  float2* cs = (float2*)d_ws;                                   // 655,360 B
  float4* qt = (float4*)((char*)d_ws + DEPTH * BDEPTH * 1024 * sizeof(float2)); // 1,032,192 B

  int prep_threads = DEPTH * BDEPTH * 1024 + (DEPTH - 1) * NQ * HALF; // 146,432
  prep_kernel<<<(prep_threads + 255) / 256, 256, 0, stream>>>(bp, sc, cs, qt);
  fwd_kernel<<<BATCH / 16, 512, 0, stream>>>(X, cs, qt, out);
}

// Round 14
// 66.347 us; speedup vs baseline: 1.8137x; 1.0680x over previous
//
#include <hip/hip_runtime.h>

#define NIN 784
#define WIDTH 1024
#define HALF 512
#define DEPTH 8
#define BDEPTH 10
#define BATCH 4096
#define SPLINE_DIM 20
#define NQ 18   // knot intervals [t_m, t_m+1), m = 2..19

typedef __attribute__((ext_vector_type(2))) float f32x2;

// Clamped knot vector T[23]: [-8]*3, +-2^k/32 ladder, 0, [8]*3
__device__ float d_T[23] = {
  -8.f, -8.f, -8.f, -4.f, -2.f, -1.f, -0.5f, -0.25f, -0.125f, -0.0625f,
  -0.03125f, 0.f, 0.03125f, 0.0625f, 0.125f, 0.25f, 0.5f, 1.f, 2.f, 4.f,
  8.f, 8.f, 8.f };

// ---------------------------------------------------------------------------
// Prep kernel (rotation math validated R3-R13). New cs layout per layer
// (10240 float2 = 80 KB):
//   d in 0..3 : [d*1024 + slot]                      = (c_d, s_d)
//   pairs p=0..2 (d=4+2p, d+1):
//               [4096 + p*2048 + slot*2 + 0]         = (c_d,   s_d)
//               [4096 + p*2048 + slot*2 + 1]         = (c_d+1, s_d+1)
//   -> one ds_read_b128 per slot feeds two consecutive steps.
// qt quadratic spline unchanged (validated R3+).
// ---------------------------------------------------------------------------
__global__ void prep_kernel(const float* __restrict__ bp,
                            const float* __restrict__ sc,
                            float2* __restrict__ cs,
                            float4* __restrict__ qt) {
  int gid = blockIdx.x * 256 + threadIdx.x;
  if (gid < DEPTH * BDEPTH * 1024) {
    int slot = gid & 1023;
    int d = (gid >> 10) % BDEPTH;
    int i = gid / (BDEPTH * 1024);
    int n = 0;
#pragma unroll
    for (int b = 0; b < 10; ++b) {
      int src = b - d; if (src < 0) src += 10;
      n |= ((slot >> src) & 1) << b;
    }
    int pj = n & 511;
    float theta = bp[(i * HALF + pj) * BDEPTH + d];
    float c = cosf(theta), s = sinf(theta);
    float2 val = make_float2(c, (n & 512) ? -s : s);
    int off;
    if (d < 4) off = i * 10240 + d * 1024 + slot;
    else {
      int p = (d - 4) >> 1, sub = (d - 4) & 1;
      off = i * 10240 + 4096 + p * 2048 + slot * 2 + sub;
    }
    cs[off] = val;
  }
  int gid2 = gid - DEPTH * BDEPTH * 1024;
  if (gid2 >= 0 && gid2 < (DEPTH - 1) * NQ * HALF) {
    int w = gid2 & 511;
    int mi = (gid2 >> 9) % NQ;
    int i = gid2 / (NQ * HALF);
    int m = mi + 2;
    const float* cf = sc + (i * HALF + w) * SPLINE_DIM;
    double c0 = cf[mi], c1 = cf[mi + 1], c2 = cf[mi + 2];
    double tm1 = d_T[m - 1], tm = d_T[m], tp1 = d_T[m + 1], tp2 = d_T[m + 2];
    double h = tp1 - tm;
    double us[3] = { 0.0, 0.5 * h, 0.75 * h };
    double y[3];
#pragma unroll
    for (int k = 0; k < 3; ++k) {
      double x = tm + us[k];
      double left1 = x - tm, right1 = tp1 - x, left2 = x - tm1, right2 = tp2 - x;
      double inv1 = 1.0 / (tp1 - tm);
      double N0 = right1 * inv1, N1 = left1 * inv1;
      double temp0 = N0 / (tp1 - tm1);
      double B0 = right1 * temp0;
      double saved = left2 * temp0;
      double temp1 = N1 / (tp2 - tm);
      double B1 = right2 * temp1 + saved;
      double B2 = left1 * temp1;
      y[k] = c0 * B0 + c1 * B1 + c2 * B2;
    }
    double d1 = y[1] - y[0], d2 = y[2] - y[0];
    double u1 = us[1], u2 = us[2];
    double det = u1 * u2 * (u2 - u1);
    double Bq = (d1 * u2 * u2 - d2 * u1 * u1) / det;
    double Cq = (d2 * u1 - d1 * u2) / det;
    qt[gid2] = make_float4((float)y[0], (float)Bq, (float)Cq, (float)tm);
  }
}

// ---------------------------------------------------------------------------
// Compile-time lane shuffles (validated): DPP xor1/2, ds_swizzle 4/8/16,
// bpermute for 32.
// ---------------------------------------------------------------------------
template <int M>
__device__ __forceinline__ float shfx(float x) {
  if constexpr (M == 1)
    return __int_as_float(__builtin_amdgcn_mov_dpp(__float_as_int(x), 0xB1, 0xF, 0xF, true));
  else if constexpr (M == 2)
    return __int_as_float(__builtin_amdgcn_mov_dpp(__float_as_int(x), 0x4E, 0xF, 0xF, true));
  else if constexpr (M == 4)
    return __int_as_float(__builtin_amdgcn_ds_swizzle(__float_as_int(x), 0x101F));
  else if constexpr (M == 8)
    return __int_as_float(__builtin_amdgcn_ds_swizzle(__float_as_int(x), 0x201F));
  else if constexpr (M == 16)
    return __int_as_float(__builtin_amdgcn_ds_swizzle(__float_as_int(x), 0x401F));
  else
    return __shfl_xor(x, 32, 64);
}

// Quadratic spline activation (validated R3+).
__device__ __forceinline__ float qspline(float x, const float4* __restrict__ qL, int w) {
  x = fminf(fmaxf(x, -8.0f), 7.9999990f);
  float ax = fabsf(x);
  unsigned bits = __float_as_uint(ax);
  int e = (int)(bits >> 23) - 127;
  int ce = e + ((bits & 0x7fffffu) ? 1 : 0);
  int m = (x > 0.f) ? (17 + e) : (5 - ce);
  m = (ax < 0.03125f) ? ((x < 0.f) ? 10 : 11) : m;
  float4 qc = qL[(m - 2) * HALF + w];
  float u = x - qc.w;
  return fmaf(u, fmaf(u, qc.z, qc.y), qc.x);
}

typedef __attribute__((address_space(3))) unsigned int lds_u32;
typedef __attribute__((address_space(1))) const unsigned int glb_u32;

// Async-stage one full layer (80 KB) into LDS buffer `dst` via global_load_lds
// (16B/lane DMA). 80 wave-segments of 1 KB; wave wv takes segs {k*8+wv},
// k=0..9 -> 10 DMAs/wave; wait with counted vmcnt(10) one layer later.
__device__ __forceinline__ void stage_async(const float2* __restrict__ src,
                                            float2* dst, int wv) {
#pragma unroll
  for (int k = 0; k < 10; ++k) {
    int seg = k * 8 + wv;
    const char* g = (const char*)src + seg * 1024 + (threadIdx.x & 63) * 16;
    char* l = (char*)dst + seg * 1024;
    __builtin_amdgcn_global_load_lds((glb_u32*)g, (lds_u32*)l, 16, 0, 0);
  }
}

// butterfly step dd<4: partner = reg ^ (8>>dd); rows packed in f32x2
#define CSTEPL(dd) do {                                                       \
    const int _mr = 8 >> (dd);                                                \
    _Pragma("unroll") for (int r = 0; r < 16; ++r)                            \
      if ((r & _mr) == 0) {                                                   \
        float2 v = cur[(dd) * 1024 + r * 64 + lane];                          \
        f32x2 a = st[r], b2 = st[r + _mr];                                    \
        f32x2 vc = {v.x, v.x}, vs = {v.y, v.y};                               \
        st[r]       = __builtin_elementwise_fma(a, vc, b2 * vs);              \
        st[r + _mr] = __builtin_elementwise_fma(b2, vc, -(a * vs));           \
      }                                                                       \
  } while (0)

// paired lane-steps: one b128 feeds steps (mask M1) then (mask M2); per-r
// chains independent, wave-lockstep keeps partner updates coherent
#define LPAIR(p, M1, M2) do {                                                 \
    const float4* _pp = (const float4*)(cur + 4096 + (p) * 2048);             \
    _Pragma("unroll") for (int r = 0; r < 16; ++r) {                          \
      float4 v = _pp[r * 64 + lane];                                          \
      f32x2 q1 = { shfx<M1>(st[r].x), shfx<M1>(st[r].y) };                    \
      st[r] = __builtin_elementwise_fma(st[r], (f32x2){v.x, v.x},             \
                                        q1 * (f32x2){v.y, v.y});              \
      f32x2 q2 = { shfx<M2>(st[r].x), shfx<M2>(st[r].y) };                    \
      st[r] = __builtin_elementwise_fma(st[r], (f32x2){v.z, v.z},             \
                                        q2 * (f32x2){v.w, v.w});              \
    }                                                                         \
  } while (0)

// ---------------------------------------------------------------------------
// Main kernel: 256 blocks x 512 threads (8 waves), TWO rows per wave packed
// into f32x2 state (v_pk_fma_f32-eligible). Full-layer 80 KB LDS staging,
// double-buffered (160 KB = whole CU LDS; grid pins 1 block/CU so it's free).
// 2 barriers/layer (was 4), one counted vmcnt(10)/layer, paired-step b128
// table reads (DS read instrs 128->80 per wave-layer).
// ---------------------------------------------------------------------------
__global__ __launch_bounds__(512, 1) void fwd_kernel(
    const float* __restrict__ X, const float2* __restrict__ cs,
    const float4* __restrict__ qt, float* __restrict__ out) {
  __shared__ float2 bufA[10240];   // 80 KB
  __shared__ float2 bufB[10240];   // 80 KB
  int tid = threadIdx.x;
  int lane = tid & 63;
  int wv = tid >> 6;                       // 0..7
  int row0 = blockIdx.x * 16 + wv * 2;

  const float* x0p = X + (long)row0 * NIN;
  const float* x1p = X + (long)(row0 + 1) * NIN;
  f32x2 st[16];
#pragma unroll
  for (int r = 0; r < 16; ++r) {
    int w = r * 64 + lane;
    bool in = (w < NIN);
    st[r] = (f32x2){ in ? x0p[w] : 0.f, in ? x1p[w] : 0.f };
  }

  // prologue: start DMA of layer 0 into bufA
  stage_async(cs, bufA, wv);

#pragma unroll 1
  for (int i = 0; i < DEPTH; ++i) {
    const float2* cur = (i & 1) ? bufB : bufA;
    float2* nxt = (i & 1) ? bufA : bufB;

    __syncthreads();                       // nxt fully consumed (prev layer)
    // issue next layer's DMA (wrap at i=7: dummy, never read)
    stage_async(cs + ((i + 1) & 7) * 10240, nxt, wv);
    asm volatile("s_waitcnt vmcnt(10)" ::: "memory");  // cur's 10 DMAs done
    __syncthreads();                       // all waves' cur DMAs landed

    CSTEPL(0);
    CSTEPL(1);
    CSTEPL(2);
    CSTEPL(3);
    LPAIR(0, 32, 16);
    LPAIR(1, 8, 4);
    LPAIR(2, 2, 1);

    if (i != DEPTH - 1) {
      const float4* qL = qt + i * (NQ * HALF);
#pragma unroll
      for (int r = 8; r < 16; ++r) {
        int w = ((r - 8) << 6) | lane;
        st[r - 8].x += qspline(st[r].x, qL, w);
        st[r - 8].y += qspline(st[r].y, qL, w);
      }
    }
  }

  float* o0 = out + (long)row0 * NIN;
  float* o1 = out + (long)(row0 + 1) * NIN;
#pragma unroll
  for (int r = 0; r < 13; ++r) {
    int w = r * 64 + lane;
    if (w < NIN) { o0[w] = st[r].x; o1[w] = st[r].y; }
  }
}

extern "C" void kernel_launch(void* const* d_in, const int* in_sizes, int n_in,
                              void* d_out, int out_size, void* d_ws, size_t ws_size,
                              hipStream_t stream) {
  const float* X  = (const float*)d_in[0];
  const float* bp = (const float*)d_in[1];   // [8,512,10]
  const float* sc = (const float*)d_in[2];   // [7,512,20]
  float* out = (float*)d_out;

  float2* cs = (float2*)d_ws;                                   // 655,360 B
  float4* qt = (float4*)((char*)d_ws + DEPTH * BDEPTH * 1024 * sizeof(float2)); // 1,032,192 B

  int prep_threads = DEPTH * BDEPTH * 1024 + (DEPTH - 1) * NQ * HALF; // 146,432
  prep_kernel<<<(prep_threads + 255) / 256, 256, 0, stream>>>(bp, sc, cs, qt);
  fwd_kernel<<<BATCH / 16, 512, 0, stream>>>(X, cs, qt, out);
}